// Round 4
// baseline (822.433 us; speedup 1.0000x reference)
//
#include <hip/hip_runtime.h>

#define EPSN 1e-12f
#define GU   8               // gathers in flight per wave in accumulate
#define WQS  16384.0f        // weight quantization scale (14 bits)

__device__ __forceinline__ float rdlane(float v, int k) {
    return __int_as_float(__builtin_amdgcn_readlane(__float_as_int(v), k));
}
__device__ __forceinline__ float preluf(float x, float a) {
    return x >= 0.0f ? x : a * x;
}

// ---------------- K1 v2: in_feat = feat_z @ weight, row-per-lane -----------
// Each lane owns one row: acc[64] in VGPRs, weight read via wave-uniform
// s_loads (SGPR operands are free in v_fma). No readlane, no AGPR spill.
__global__ __launch_bounds__(256) void k_transform2(
    const float* __restrict__ feat, const float* __restrict__ weight,
    const float* __restrict__ bias, const float* __restrict__ prelu_a,
    float* __restrict__ in_feat, float* __restrict__ out_anchor,
    int N, int totalWaves)
{
    const int lane  = threadIdx.x & 63;
    const int wid   = (int)((blockIdx.x * (size_t)blockDim.x + threadIdx.x) >> 6);
    const int tiles = (N + 63) >> 6;

    for (int tile = wid; tile < tiles; tile += totalWaves) {
        const int row = tile * 64 + lane;
        if (row >= N) continue;

        float acc[64];
        #pragma unroll
        for (int j = 0; j < 64; ++j) acc[j] = 0.0f;

        const float4* fp = (const float4*)(feat + (size_t)row * 128);
        for (int kc = 0; kc < 32; ++kc) {              // k in chunks of 4
            const float4 f = fp[kc];
            const float fs[4] = {f.x, f.y, f.z, f.w};
            #pragma unroll
            for (int kk = 0; kk < 4; ++kk) {
                const float fv = fs[kk];
                const float* wr = weight + (kc * 4 + kk) * 64;  // uniform addr
                #pragma unroll
                for (int j = 0; j < 64; ++j)
                    acc[j] = fmaf(fv, wr[j], acc[j]);
            }
        }

        float* op = in_feat + (size_t)row * 64;
        if ((row & 3) == 0) {
            const float a = prelu_a[0];
            float ss = 0.0f;
            #pragma unroll
            for (int j = 0; j < 64; ++j) {
                acc[j] = preluf(acc[j] + bias[j], a);
                ss = fmaf(acc[j], acc[j], ss);
            }
            const float inv = 1.0f / fmaxf(sqrtf(ss), EPSN);
            float* ap = out_anchor + (size_t)(row >> 2) * 64;
            #pragma unroll
            for (int j = 0; j < 64; ++j) ap[j] = acc[j] * inv;
            #pragma unroll
            for (int j = 0; j < 64; ++j) op[j] = 0.0f;   // for fallback path
        } else {
            #pragma unroll
            for (int j = 0; j < 64; ++j) op[j] = acc[j];
        }
    }
}

// ---------------- C1: per-row edge counts (global atomics, 262k counters) --
// drops zero-message edges (src % 4 == 0 -> in_feat row is zero)
__global__ __launch_bounds__(256) void c_count(
    const int* __restrict__ esrc, const int* __restrict__ edst, int E,
    unsigned* __restrict__ cnt)
{
    const int idx0   = blockIdx.x * blockDim.x + threadIdx.x;
    const int stride = gridDim.x * blockDim.x;
    for (int i = idx0; i < E; i += 4 * stride) {
        int d[4];
        #pragma unroll
        for (int u = 0; u < 4; ++u) {
            const int ii = i + u * stride;
            d[u] = -1;
            if (ii < E) {
                const int s = esrc[ii];
                if ((s & 3) != 0) d[u] = edst[ii];
            }
        }
        #pragma unroll
        for (int u = 0; u < 4; ++u)
            if (d[u] >= 0) atomicAdd(&cnt[d[u]], 1u);
    }
}

// ---------------- C2a: per-256-block scan of cnt -> rs (local) + T ---------
__global__ __launch_bounds__(256) void c_scan1(
    const unsigned* __restrict__ cnt, unsigned* __restrict__ rs,
    unsigned* __restrict__ T, int N)
{
    __shared__ unsigned sc[256];
    const int t = threadIdx.x;
    const int i = blockIdx.x * 256 + t;
    const unsigned my = (i < N) ? cnt[i] : 0u;
    sc[t] = my;
    __syncthreads();
    for (int off = 1; off < 256; off <<= 1) {
        unsigned v = (t >= off) ? sc[t - off] : 0u;
        __syncthreads();
        sc[t] += v;
        __syncthreads();
    }
    if (i < N) rs[i] = sc[t] - my;
    if (t == 255) T[blockIdx.x] = sc[255];
}

// ---------------- C2b: scan block totals (single block, <=1024) ------------
__global__ __launch_bounds__(1024) void c_scan2(
    unsigned* __restrict__ T, unsigned* __restrict__ total_out, int nT)
{
    __shared__ unsigned sc[1024];
    const int t = threadIdx.x;
    const unsigned my = (t < nT) ? T[t] : 0u;
    sc[t] = my;
    __syncthreads();
    for (int off = 1; off < 1024; off <<= 1) {
        unsigned v = (t >= off) ? sc[t - off] : 0u;
        __syncthreads();
        sc[t] += v;
        __syncthreads();
    }
    if (t < nT) T[t] = sc[t] - my;            // in-place exclusive
    if (t == 1023) *total_out = sc[1023];     // rs[N]
}

// ---------------- C2c: add block bases; init cursors -----------------------
__global__ __launch_bounds__(256) void c_scan3(
    unsigned* __restrict__ rs, unsigned* __restrict__ cur,
    const unsigned* __restrict__ T, int N)
{
    const int i = blockIdx.x * 256 + threadIdx.x;
    if (i < N) {
        const unsigned v = rs[i] + T[blockIdx.x];
        rs[i]  = v;
        cur[i] = v;
    }
}

// ---------------- C3: scatter directly into final row-sorted position ------
// record: src (bits 0..17) | wq (bits 18..31)
__global__ __launch_bounds__(256) void c_scatter(
    const int* __restrict__ esrc, const int* __restrict__ edst,
    const float* __restrict__ ew, int E,
    unsigned* __restrict__ cur, unsigned* __restrict__ recf)
{
    const int idx0   = blockIdx.x * blockDim.x + threadIdx.x;
    const int stride = gridDim.x * blockDim.x;
    for (int i = idx0; i < E; i += 4 * stride) {
        int sv[4], dv[4]; unsigned wq[4];
        #pragma unroll
        for (int u = 0; u < 4; ++u) {
            const int ii = i + u * stride;
            dv[u] = -1;
            if (ii < E) {
                const int s = esrc[ii];
                if ((s & 3) != 0) {
                    sv[u] = s;
                    dv[u] = edst[ii];
                    wq[u] = min((unsigned)(ew[ii] * WQS + 0.5f), 16383u);
                }
            }
        }
        unsigned slot[4];
        #pragma unroll
        for (int u = 0; u < 4; ++u)
            if (dv[u] >= 0) slot[u] = atomicAdd(&cur[dv[u]], 1u);
        #pragma unroll
        for (int u = 0; u < 4; ++u)
            if (dv[u] >= 0)
                recf[slot[u]] = ((unsigned)sv[u]) | (wq[u] << 18);
    }
}

// ---------------- S5: one wave per dst row, register accumulation ----------
__global__ __launch_bounds__(256) void s_accum4(
    const float* __restrict__ in_feat, const unsigned* __restrict__ recf,
    const unsigned* __restrict__ rs, float* __restrict__ h,
    int NROWS, int totalWaves)
{
    const int lane = threadIdx.x & 63;
    const int wid = (int)((blockIdx.x * (size_t)blockDim.x + threadIdx.x) >> 6);

    for (int row = wid; row < NROWS; row += totalWaves) {
        const unsigned s = rs[row], e = rs[row + 1];
        float acc = 0.0f;
        unsigned done = s;
        while (done < e) {
            const int c = (int)min(64u, e - done);
            unsigned rcd = 0u;
            if (lane < c) rcd = recf[done + lane];   // coalesced 4B x c
            for (int j0 = 0; j0 < c; j0 += GU) {
                float v[GU], wj[GU];
                #pragma unroll
                for (int jj = 0; jj < GU; ++jj) {
                    const int idx = j0 + jj;
                    const int cl  = (idx < c) ? idx : (c - 1);
                    const unsigned px =
                        (unsigned)__builtin_amdgcn_readlane((int)rcd, cl);
                    v[jj]  = in_feat[((size_t)(px & 0x3FFFFu) << 6) + lane];
                    wj[jj] = (idx < c) ? (float)(px >> 18) : 0.0f;
                }
                #pragma unroll
                for (int jj = 0; jj < GU; ++jj) acc = fmaf(v[jj], wj[jj], acc);
            }
            done += (unsigned)c;
        }
        h[((size_t)row << 6) + lane] = acc * (1.0f / WQS);
    }
}

// ---------------- fallback K2 (atomic scatter) ----------------------------
#define K2_U 8
__global__ __launch_bounds__(256) void k_edges(
    const float* __restrict__ in_feat, const int* __restrict__ esrc,
    const int* __restrict__ edst, const float* __restrict__ ew,
    float* __restrict__ h, int E, int totalWaves)
{
    const int lane = threadIdx.x & 63;
    int wid = (int)((blockIdx.x * (size_t)blockDim.x + threadIdx.x) >> 6);
    wid = __builtin_amdgcn_readfirstlane(wid);
    const int chunk = (E + totalWaves - 1) / totalWaves;
    int e0 = wid * chunk;
    int e1 = min(e0 + chunk, E);
    for (int base = e0; base < e1; base += K2_U) {
        const int nb = min(K2_U, e1 - base);
        int s[K2_U], d[K2_U]; float w[K2_U];
        #pragma unroll
        for (int j = 0; j < K2_U; ++j) {
            int idx = base + ((j < nb) ? j : 0);
            s[j] = esrc[idx]; d[j] = edst[idx]; w[j] = ew[idx];
        }
        float v[K2_U];
        #pragma unroll
        for (int j = 0; j < K2_U; ++j)
            v[j] = in_feat[((size_t)s[j] << 6) + lane];
        #pragma unroll
        for (int j = 0; j < K2_U; ++j)
            if (j < nb) atomicAdd(h + ((size_t)d[j] << 6) + lane, v[j] * w[j]);
    }
}

// ---------------- K3: activation + pool + two GEMVs + l2norm --------------
__global__ __launch_bounds__(256) void k_finalize(
    const float* __restrict__ h, const float* __restrict__ bias,
    const float* __restrict__ prelu_a,
    const float* __restrict__ w_sub, const float* __restrict__ b_sub,
    const float* __restrict__ w_gcn, const float* __restrict__ b_gcn,
    float* __restrict__ out_sub, float* __restrict__ out_gcn,
    int G, int totalWaves)
{
    const int lane = threadIdx.x & 63;
    const int wid = (int)((blockIdx.x * (size_t)blockDim.x + threadIdx.x) >> 6);

    float wsreg[64], wgreg[64];
    #pragma unroll
    for (int k = 0; k < 64; ++k) wsreg[k] = w_sub[lane * 64 + k];
    #pragma unroll
    for (int k = 0; k < 64; ++k) wgreg[k] = w_gcn[lane * 64 + k];
    const float bj  = bias[lane];
    const float bsj = b_sub[lane];
    const float bgj = b_gcn[lane];
    const float a   = prelu_a[0];

    for (int g = wid; g < G; g += totalWaves) {
        const float* hp = h + (size_t)g * 256;
        float p0 = preluf(hp[lane]       + bj, a);
        float p1 = preluf(hp[64  + lane] + bj, a);
        float p2 = preluf(hp[128 + lane] + bj, a);
        float p3 = preluf(hp[192 + lane] + bj, a);
        float pool = (p0 + p1 + p2 + p3) * 0.25f;
        float gcn  = p0;

        float as = bsj, ag = bgj;
        #pragma unroll
        for (int k = 0; k < 64; ++k) {
            as = fmaf(rdlane(pool, k), wsreg[k], as);
            ag = fmaf(rdlane(gcn,  k), wgreg[k], ag);
        }
        float ss = as * as, sg = ag * ag;
        #pragma unroll
        for (int off = 32; off >= 1; off >>= 1) {
            ss += __shfl_xor(ss, off, 64);
            sg += __shfl_xor(sg, off, 64);
        }
        out_sub[(size_t)g * 64 + lane] = as / fmaxf(sqrtf(ss), EPSN);
        out_gcn[(size_t)g * 64 + lane] = ag / fmaxf(sqrtf(sg), EPSN);
    }
}

extern "C" void kernel_launch(void* const* d_in, const int* in_sizes, int n_in,
                              void* d_out, int out_size, void* d_ws, size_t ws_size,
                              hipStream_t stream)
{
    const float* feat    = (const float*)d_in[0];
    const int*   esrc    = (const int*)  d_in[1];
    const int*   edst    = (const int*)  d_in[2];
    const float* ew      = (const float*)d_in[3];
    const float* weight  = (const float*)d_in[4];
    const float* bias    = (const float*)d_in[5];
    const float* prelu_a = (const float*)d_in[6];
    const float* w_sub   = (const float*)d_in[7];
    const float* b_sub   = (const float*)d_in[8];
    const float* w_gcn   = (const float*)d_in[9];
    const float* b_gcn   = (const float*)d_in[10];

    const int N = in_sizes[0] / 128;
    const int E = in_sizes[1];
    const int G = N / 4;
    const int nT = (N + 255) / 256;

    // ws layout (bytes). A = N*64*4:
    //   in_feat : [0, A)
    //   h       : [A, 2A)
    //   recf    : [2A, 2A+E*4)
    //   cnt     : N*4
    //   rs      : (N+1)*4
    //   cur     : N*4
    //   T       : nT*4
    char* wsb = (char*)d_ws;
    const size_t A      = (size_t)N * 64 * 4;
    const size_t offRf  = 2 * A;
    const size_t offCnt = offRf  + (size_t)E * 4;
    const size_t offRs  = offCnt + (size_t)N * 4;
    const size_t offCur = offRs  + (size_t)(N + 1) * 4;
    const size_t offT   = offCur + (size_t)N * 4;
    const size_t ws_need = offT + (size_t)nT * 4;

    float*    in_feat = (float*)wsb;
    float*    h       = (float*)(wsb + A);
    unsigned* recf    = (unsigned*)(wsb + offRf);
    unsigned* cnt     = (unsigned*)(wsb + offCnt);
    unsigned* rs      = (unsigned*)(wsb + offRs);
    unsigned* cur     = (unsigned*)(wsb + offCur);
    unsigned* T       = (unsigned*)(wsb + offT);

    float* out        = (float*)d_out;
    float* out_sub    = out;
    float* out_anchor = out + (size_t)G * 64;
    float* out_gcn    = out + (size_t)2 * G * 64;

    // src must fit 18 bits; nT must fit single-block scan
    const bool sorted_path =
        (N <= (1 << 18)) && (nT <= 1024) && (ws_size >= ws_need);

    {   // K1
        const int blocks = 1024, tw = blocks * 4;
        k_transform2<<<blocks, 256, 0, stream>>>(feat, weight, bias, prelu_a,
                                                 in_feat, out_anchor, N, tw);
    }

    if (sorted_path) {
        hipMemsetAsync(cnt, 0, (size_t)N * sizeof(unsigned), stream);
        c_count  <<<2048, 256, 0, stream>>>(esrc, edst, E, cnt);
        c_scan1  <<<nT, 256, 0, stream>>>(cnt, rs, T, N);
        c_scan2  <<<1, 1024, 0, stream>>>(T, rs + N, nT);
        c_scan3  <<<nT, 256, 0, stream>>>(rs, cur, T, N);
        c_scatter<<<2048, 256, 0, stream>>>(esrc, edst, ew, E, cur, recf);
        {
            const int blocks = 2048, tw = blocks * 4;   // 8192 waves, 32 rows each
            s_accum4<<<blocks, 256, 0, stream>>>(in_feat, recf, rs, h, N, tw);
        }
        {
            const int blocks = 4096, tw = blocks * 4;
            k_finalize<<<blocks, 256, 0, stream>>>(h, bias, prelu_a, w_sub, b_sub,
                                                   w_gcn, b_gcn, out_sub, out_gcn, G, tw);
        }
    } else if (ws_size >= 2 * A) {
        hipMemsetAsync(h, 0, A, stream);
        const int blocks = 2048, tw = blocks * 4;
        k_edges<<<blocks, 256, 0, stream>>>(in_feat, esrc, edst, ew, h, E, tw);
        const int fblocks = 4096, ftw = fblocks * 4;
        k_finalize<<<fblocks, 256, 0, stream>>>(h, bias, prelu_a, w_sub, b_sub,
                                                w_gcn, b_gcn, out_sub, out_gcn, G, ftw);
    }
}

// Round 5
// 601.188 us; speedup vs baseline: 1.3680x; 1.3680x over previous
//
#include <hip/hip_runtime.h>

#define EPSN 1e-12f
#define NB   1024            // coarse dst buckets (dst >> 8)
#define RB   256             // rows per coarse bucket (N / NB)
#define CHK  4096            // edges per count/scatter workgroup
#define NWGMAX 2048          // scanA supports up to 2048 edge blocks (PER=8)
#define GU   16              // gathers in flight per wave in accumulate
#define WQS  16384.0f        // weight quantization scale (14 bits)

__device__ __forceinline__ float rdlane(float v, int k) {
    return __int_as_float(__builtin_amdgcn_readlane(__float_as_int(v), k));
}
__device__ __forceinline__ float preluf(float x, float a) {
    return x >= 0.0f ? x : a * x;
}

// ---------------- K1 v2: in_feat = feat_z @ weight, row-per-lane -----------
// Each lane owns one row: acc[64] in VGPRs, weight read via wave-uniform
// loads (SGPR/broadcast operands). No readlane, no AGPR spill.
__global__ __launch_bounds__(256) void k_transform2(
    const float* __restrict__ feat, const float* __restrict__ weight,
    const float* __restrict__ bias, const float* __restrict__ prelu_a,
    float* __restrict__ in_feat, float* __restrict__ out_anchor,
    int N, int totalWaves)
{
    const int lane  = threadIdx.x & 63;
    const int wid   = (int)((blockIdx.x * (size_t)blockDim.x + threadIdx.x) >> 6);
    const int tiles = (N + 63) >> 6;

    for (int tile = wid; tile < tiles; tile += totalWaves) {
        const int row = tile * 64 + lane;
        if (row >= N) continue;

        float acc[64];
        #pragma unroll
        for (int j = 0; j < 64; ++j) acc[j] = 0.0f;

        const float4* fp = (const float4*)(feat + (size_t)row * 128);
        for (int kc = 0; kc < 32; ++kc) {              // k in chunks of 4
            const float4 f = fp[kc];
            const float fs[4] = {f.x, f.y, f.z, f.w};
            #pragma unroll
            for (int kk = 0; kk < 4; ++kk) {
                const float fv = fs[kk];
                const float* wr = weight + (kc * 4 + kk) * 64;  // uniform addr
                #pragma unroll
                for (int j = 0; j < 64; ++j)
                    acc[j] = fmaf(fv, wr[j], acc[j]);
            }
        }

        float4* op4 = (float4*)(in_feat + (size_t)row * 64);
        if ((row & 3) == 0) {
            const float a = prelu_a[0];
            float ss = 0.0f;
            #pragma unroll
            for (int j = 0; j < 64; ++j) {
                acc[j] = preluf(acc[j] + bias[j], a);
                ss = fmaf(acc[j], acc[j], ss);
            }
            const float inv = 1.0f / fmaxf(sqrtf(ss), EPSN);
            float4* ap4 = (float4*)(out_anchor + (size_t)(row >> 2) * 64);
            #pragma unroll
            for (int j4 = 0; j4 < 16; ++j4)
                ap4[j4] = make_float4(acc[4*j4]*inv, acc[4*j4+1]*inv,
                                      acc[4*j4+2]*inv, acc[4*j4+3]*inv);
            const float4 z = make_float4(0.f, 0.f, 0.f, 0.f);
            #pragma unroll
            for (int j4 = 0; j4 < 16; ++j4) op4[j4] = z;   // for fallback path
        } else {
            #pragma unroll
            for (int j4 = 0; j4 < 16; ++j4)
                op4[j4] = make_float4(acc[4*j4], acc[4*j4+1],
                                      acc[4*j4+2], acc[4*j4+3]);
        }
    }
}

// ---------------- S1: per-block bucket histograms (NO global atomics) ------
// drops zero-message edges (src % 4 == 0 -> in_feat row is zero)
__global__ __launch_bounds__(256) void s_count2(
    const int* __restrict__ esrc, const int* __restrict__ edst, int E,
    unsigned* __restrict__ C)
{
    __shared__ unsigned hist[NB];
    for (int i = threadIdx.x; i < NB; i += 256) hist[i] = 0;
    __syncthreads();
    const int base = blockIdx.x * CHK;
    #pragma unroll
    for (int i = 0; i < 16; ++i) {
        int idx = base + i * 256 + threadIdx.x;
        if (idx < E) {
            int s = esrc[idx];
            if ((s & 3) != 0)
                atomicAdd(&hist[((unsigned)edst[idx]) >> 8], 1u);
        }
    }
    __syncthreads();
    for (int i = threadIdx.x; i < NB; i += 256)
        C[(size_t)blockIdx.x * NB + i] = hist[i];
}

// ---------------- S2a: per-bucket exclusive scan over blocks, IN PLACE -----
// block i scans C[blk][i] over blk; rewrites C[blk][i] = excl prefix; T[i]=sum
__global__ __launch_bounds__(256) void s_scanA(
    unsigned* __restrict__ C, unsigned* __restrict__ T, int nwg)
{
    __shared__ unsigned ssum[256];
    const int i = blockIdx.x;
    const int t = threadIdx.x;
    unsigned vals[8];
    unsigned run = 0;
    #pragma unroll
    for (int p = 0; p < 8; ++p) {
        const int blk = t * 8 + p;
        const unsigned v = (blk < nwg) ? C[(size_t)blk * NB + i] : 0u;
        vals[p] = run;
        run += v;
    }
    ssum[t] = run;
    __syncthreads();
    for (int off = 1; off < 256; off <<= 1) {
        unsigned x = (t >= off) ? ssum[t - off] : 0u;
        __syncthreads();
        ssum[t] += x;
        __syncthreads();
    }
    const unsigned texcl = ssum[t] - run;
    #pragma unroll
    for (int p = 0; p < 8; ++p) {
        const int blk = t * 8 + p;
        if (blk < nwg) C[(size_t)blk * NB + i] = texcl + vals[p];
    }
    if (t == 255) T[i] = ssum[255];
}

// ---------------- S2b: exclusive scan over NB bucket totals ----------------
__global__ __launch_bounds__(1024) void s_scanB(
    const unsigned* __restrict__ T, unsigned* __restrict__ basep,
    unsigned* __restrict__ rs, int N)
{
    __shared__ unsigned sc[NB];
    const int t = threadIdx.x;
    unsigned my = T[t];
    sc[t] = my;
    __syncthreads();
    for (int off = 1; off < NB; off <<= 1) {
        unsigned a = (t >= off) ? sc[t - off] : 0u;
        __syncthreads();
        sc[t] += a;
        __syncthreads();
    }
    basep[t] = sc[t] - my;
    if (t == NB - 1) { basep[NB] = sc[t]; rs[N] = sc[t]; }
}

// ---------------- S3: scatter into coarse-sorted records (LDS cursors only)
__global__ __launch_bounds__(256) void s_scatter3(
    const int* __restrict__ esrc, const int* __restrict__ edst,
    const float* __restrict__ ew, int E,
    const unsigned* __restrict__ basep, const unsigned* __restrict__ PT,
    uint2* __restrict__ recs)
{
    __shared__ unsigned cur[NB];
    const int blk = blockIdx.x;
    for (int i = threadIdx.x; i < NB; i += 256)
        cur[i] = basep[i] + PT[(size_t)blk * NB + i];
    __syncthreads();
    const int base = blk * CHK;
    int s[16], d[16]; float wv[16];
    #pragma unroll
    for (int i = 0; i < 16; ++i) {
        int idx = base + i * 256 + threadIdx.x;
        const bool ok = (idx < E);
        s[i]  = ok ? esrc[idx] : 0;
        d[i]  = ok ? edst[idx] : 0;
        wv[i] = ok ? ew[idx]   : 0.0f;
        if (!ok || (s[i] & 3) == 0) d[i] = -1;   // pad or anchor-src: skip
    }
    #pragma unroll
    for (int i = 0; i < 16; ++i) {
        if (d[i] >= 0) {
            const unsigned slot = atomicAdd(&cur[((unsigned)d[i]) >> 8], 1u);
            const unsigned pack =
                ((unsigned)s[i]) | ((((unsigned)d[i]) & 255u) << 18);
            recs[slot] = make_uint2(pack, __float_as_uint(wv[i]));
        }
    }
}

// ---------------- S4: per-bucket fine sort -> 4B records -------------------
// output record: src (bits 0..17) | wq (bits 18..31), wq = round(w * 16384)
__global__ __launch_bounds__(256) void s_sortfine(
    const uint2* __restrict__ recs, const unsigned* __restrict__ basep,
    unsigned* __restrict__ recf, unsigned* __restrict__ rs)
{
    __shared__ unsigned hist[RB], sc[RB], cur[RB];
    const int t = threadIdx.x;
    const int b = blockIdx.x;
    const unsigned start = basep[b], end = basep[b + 1];
    hist[t] = 0;
    __syncthreads();
    for (unsigned i = start + t; i < end; i += 256)
        atomicAdd(&hist[recs[i].x >> 18], 1u);
    __syncthreads();
    sc[t] = hist[t];
    __syncthreads();
    for (int off = 1; off < RB; off <<= 1) {
        unsigned v = (t >= off) ? sc[t - off] : 0u;
        __syncthreads();
        sc[t] += v;
        __syncthreads();
    }
    const unsigned excl = sc[t] - hist[t];
    cur[t] = start + excl;
    rs[b * RB + t] = start + excl;
    __syncthreads();
    for (unsigned i = start + t; i < end; i += 256) {
        uint2 r = recs[i];
        unsigned slot = atomicAdd(&cur[r.x >> 18], 1u);
        unsigned wq = (unsigned)(__uint_as_float(r.y) * WQS + 0.5f);
        wq = min(wq, 16383u);
        recf[slot] = (r.x & 0x3FFFFu) | (wq << 18);
    }
}

// ---------------- S5: one wave per dst row, register accumulation ----------
// lean: no LDS, minimal VGPR -> max occupancy for the latency-bound gather.
// 4B records: 1 readlane/edge; integer weights accumulated, scaled once/row.
__global__ __launch_bounds__(256) void s_accum4(
    const float* __restrict__ in_feat, const unsigned* __restrict__ recf,
    const unsigned* __restrict__ rs, float* __restrict__ h,
    int NROWS, int totalWaves)
{
    const int lane = threadIdx.x & 63;
    const int wid = (int)((blockIdx.x * (size_t)blockDim.x + threadIdx.x) >> 6);

    for (int row = wid; row < NROWS; row += totalWaves) {
        const unsigned s = rs[row], e = rs[row + 1];
        float acc = 0.0f;
        unsigned done = s;
        while (done < e) {
            const int c = (int)min(64u, e - done);
            unsigned rcd = 0u;
            if (lane < c) rcd = recf[done + lane];   // coalesced 4B x c
            for (int j0 = 0; j0 < c; j0 += GU) {
                float v[GU], wj[GU];
                #pragma unroll
                for (int jj = 0; jj < GU; ++jj) {
                    const int idx = j0 + jj;
                    const int cl  = (idx < c) ? idx : (c - 1);
                    const unsigned px =
                        (unsigned)__builtin_amdgcn_readlane((int)rcd, cl);
                    v[jj]  = in_feat[((size_t)(px & 0x3FFFFu) << 6) + lane];
                    wj[jj] = (idx < c) ? (float)(px >> 18) : 0.0f;
                }
                #pragma unroll
                for (int jj = 0; jj < GU; ++jj) acc = fmaf(v[jj], wj[jj], acc);
            }
            done += (unsigned)c;
        }
        h[((size_t)row << 6) + lane] = acc * (1.0f / WQS);
    }
}

// ---------------- fallback K2 (atomic scatter) ----------------------------
#define K2_U 8
__global__ __launch_bounds__(256) void k_edges(
    const float* __restrict__ in_feat, const int* __restrict__ esrc,
    const int* __restrict__ edst, const float* __restrict__ ew,
    float* __restrict__ h, int E, int totalWaves)
{
    const int lane = threadIdx.x & 63;
    int wid = (int)((blockIdx.x * (size_t)blockDim.x + threadIdx.x) >> 6);
    wid = __builtin_amdgcn_readfirstlane(wid);
    const int chunk = (E + totalWaves - 1) / totalWaves;
    int e0 = wid * chunk;
    int e1 = min(e0 + chunk, E);
    for (int base = e0; base < e1; base += K2_U) {
        const int nb = min(K2_U, e1 - base);
        int s[K2_U], d[K2_U]; float w[K2_U];
        #pragma unroll
        for (int j = 0; j < K2_U; ++j) {
            int idx = base + ((j < nb) ? j : 0);
            s[j] = esrc[idx]; d[j] = edst[idx]; w[j] = ew[idx];
        }
        float v[K2_U];
        #pragma unroll
        for (int j = 0; j < K2_U; ++j)
            v[j] = in_feat[((size_t)s[j] << 6) + lane];
        #pragma unroll
        for (int j = 0; j < K2_U; ++j)
            if (j < nb) atomicAdd(h + ((size_t)d[j] << 6) + lane, v[j] * w[j]);
    }
}

// ---------------- K3: activation + pool + two GEMVs + l2norm --------------
__global__ __launch_bounds__(256) void k_finalize(
    const float* __restrict__ h, const float* __restrict__ bias,
    const float* __restrict__ prelu_a,
    const float* __restrict__ w_sub, const float* __restrict__ b_sub,
    const float* __restrict__ w_gcn, const float* __restrict__ b_gcn,
    float* __restrict__ out_sub, float* __restrict__ out_gcn,
    int G, int totalWaves)
{
    const int lane = threadIdx.x & 63;
    const int wid = (int)((blockIdx.x * (size_t)blockDim.x + threadIdx.x) >> 6);

    float wsreg[64], wgreg[64];
    #pragma unroll
    for (int k = 0; k < 64; ++k) wsreg[k] = w_sub[lane * 64 + k];
    #pragma unroll
    for (int k = 0; k < 64; ++k) wgreg[k] = w_gcn[lane * 64 + k];
    const float bj  = bias[lane];
    const float bsj = b_sub[lane];
    const float bgj = b_gcn[lane];
    const float a   = prelu_a[0];

    for (int g = wid; g < G; g += totalWaves) {
        const float* hp = h + (size_t)g * 256;
        float p0 = preluf(hp[lane]       + bj, a);
        float p1 = preluf(hp[64  + lane] + bj, a);
        float p2 = preluf(hp[128 + lane] + bj, a);
        float p3 = preluf(hp[192 + lane] + bj, a);
        float pool = (p0 + p1 + p2 + p3) * 0.25f;
        float gcn  = p0;

        float as = bsj, ag = bgj;
        #pragma unroll
        for (int k = 0; k < 64; ++k) {
            as = fmaf(rdlane(pool, k), wsreg[k], as);
            ag = fmaf(rdlane(gcn,  k), wgreg[k], ag);
        }
        float ss = as * as, sg = ag * ag;
        #pragma unroll
        for (int off = 32; off >= 1; off >>= 1) {
            ss += __shfl_xor(ss, off, 64);
            sg += __shfl_xor(sg, off, 64);
        }
        out_sub[(size_t)g * 64 + lane] = as / fmaxf(sqrtf(ss), EPSN);
        out_gcn[(size_t)g * 64 + lane] = ag / fmaxf(sqrtf(sg), EPSN);
    }
}

extern "C" void kernel_launch(void* const* d_in, const int* in_sizes, int n_in,
                              void* d_out, int out_size, void* d_ws, size_t ws_size,
                              hipStream_t stream)
{
    const float* feat    = (const float*)d_in[0];
    const int*   esrc    = (const int*)  d_in[1];
    const int*   edst    = (const int*)  d_in[2];
    const float* ew      = (const float*)d_in[3];
    const float* weight  = (const float*)d_in[4];
    const float* bias    = (const float*)d_in[5];
    const float* prelu_a = (const float*)d_in[6];
    const float* w_sub   = (const float*)d_in[7];
    const float* b_sub   = (const float*)d_in[8];
    const float* w_gcn   = (const float*)d_in[9];
    const float* b_gcn   = (const float*)d_in[10];

    const int N = in_sizes[0] / 128;
    const int E = in_sizes[1];
    const int G = N / 4;
    const int nwg = (E + CHK - 1) / CHK;

    // ws layout (sorted path; bytes). A = N*64*4 = 67.1 MB:
    //   in_feat : [0, A)
    //   h       : [A, 2A)        -- written by s_accum4 (after sortfine)
    //   recs    : [A, A+E*8)     -- overlays h; dead before s_accum4 runs
    //   recf    : [2A, 2A+E*4)
    //   C       : [.., +nwg*NB*4)   (scanned IN PLACE; doubles as PT)
    //   T       : NB*4
    //   basep   : (NB+1)*4
    //   rs      : (N+1)*4
    char* wsb = (char*)d_ws;
    const size_t A     = (size_t)N * 64 * 4;
    const size_t offRf = 2 * A;
    const size_t offC  = offRf + (size_t)E * 4;
    const size_t offT  = offC  + (size_t)nwg * NB * 4;
    const size_t offBp = offT  + (size_t)NB * 4;
    const size_t offRs = offBp + (size_t)(NB + 1) * 4;
    const size_t ws_need = offRs + (size_t)(N + 1) * 4;

    float*    in_feat = (float*)wsb;
    float*    h       = (float*)(wsb + A);
    uint2*    recs    = (uint2*)(wsb + A);
    unsigned* recf    = (unsigned*)(wsb + offRf);
    unsigned* C       = (unsigned*)(wsb + offC);
    unsigned* T       = (unsigned*)(wsb + offT);
    unsigned* basep   = (unsigned*)(wsb + offBp);
    unsigned* rs      = (unsigned*)(wsb + offRs);

    float* out        = (float*)d_out;
    float* out_sub    = out;
    float* out_anchor = out + (size_t)G * 64;
    float* out_gcn    = out + (size_t)2 * G * 64;

    const bool sorted_path =
        (N == NB * RB) && (nwg <= NWGMAX) && (ws_size >= ws_need);

    {   // K1: one tile (64 rows) per wave
        const int blocks = 1024, tw = blocks * 4;
        k_transform2<<<blocks, 256, 0, stream>>>(feat, weight, bias, prelu_a,
                                                 in_feat, out_anchor, N, tw);
    }

    if (sorted_path) {
        s_count2  <<<nwg, 256, 0, stream>>>(esrc, edst, E, C);
        s_scanA   <<<NB, 256, 0, stream>>>(C, T, nwg);
        s_scanB   <<<1, 1024, 0, stream>>>(T, basep, rs, N);
        s_scatter3<<<nwg, 256, 0, stream>>>(esrc, edst, ew, E, basep, C, recs);
        s_sortfine<<<NB, 256, 0, stream>>>(recs, basep, recf, rs);
        {
            const int blocks = 2048, tw = blocks * 4;   // 8192 waves, 32 rows each
            s_accum4<<<blocks, 256, 0, stream>>>(in_feat, recf, rs, h, N, tw);
        }
        {
            const int blocks = 4096, tw = blocks * 4;
            k_finalize<<<blocks, 256, 0, stream>>>(h, bias, prelu_a, w_sub, b_sub,
                                                   w_gcn, b_gcn, out_sub, out_gcn, G, tw);
        }
    } else if (ws_size >= 2 * A) {
        hipMemsetAsync(h, 0, A, stream);
        const int blocks = 2048, tw = blocks * 4;
        k_edges<<<blocks, 256, 0, stream>>>(in_feat, esrc, edst, ew, h, E, tw);
        const int fblocks = 4096, ftw = fblocks * 4;
        k_finalize<<<fblocks, 256, 0, stream>>>(h, bias, prelu_a, w_sub, b_sub,
                                                w_gcn, b_gcn, out_sub, out_gcn, G, ftw);
    }
}